// Round 5
// baseline (815.010 us; speedup 1.0000x reference)
//
#include <hip/hip_runtime.h>

// ---------------------------------------------------------------------------
// YOLO NMS post-processing for MI355X — SINGLE persistent kernel.
//
// 5 rounds of evidence: every individual kernel <= 48 us, sum of work ~90 us,
// total ~220 us -> ~130 us is launch boundaries + harness fill. Fix: fuse the
// whole pipeline into ONE 256-block persistent kernel with device-scope grid
// barriers. Co-residency is GUARANTEED: 125 KB static LDS per block means 2
// blocks/CU is impossible, so 256 blocks spread over 256 CUs.
//
// Phases (grid barriers between): score (LDS tile + LDS-local histogram,
// flushed via device atomics -> no slices/zero/reduce kernels) -> select
// (block 0) -> compact -> rank (single-pass per key: no zeroing, no atomics)
// -> scatter -> iou (PACKED upper-tri 64x64-tile bitmask) -> scan (block 0,
// one wave) -> output (all blocks).
//
// Cross-XCD safety: barriers use device-scope atomics + __threadfence
// (release before arrive / acquire after pass). Additionally every buffer is
// FIRST-TOUCHED by reader XCDs only after its producing phase (rank is
// written single-pass, not zeroed+atomic'd, precisely to keep this property),
// and device-scope atomics (hist, sel[2]) operate at the coherence point.
//
// Scan = speculative candidate pipeline (replaces 64-batch serial loop whose
// ~1700 cy/batch dependent-LDS chains were the invariant floor across 4
// structures): alive = 4096 bits (1 u64/lane). A 16-deep register FIFO of
// prefetched candidate rows (plain per-lane loads; backend emits counted
// vmcnt). Pop head -> readlane alive-test -> keep: suppress from register row
// (alive &= ~row); discard costs nothing. Refill = wave ballot find-next-bit.
// Iterations ~= keeps (~300) + rare local discards; memory fully overlapped.
// Greedy order provably identical to reference (candidates processed in
// ascending slot order, suppression applied before each later test).
//
// All IoU-relevant fp32 math uses _rn intrinsics so hipcc's default
// -ffp-contract=fast cannot fuse mul+add into fma (must match numpy fp32).
// ---------------------------------------------------------------------------

typedef unsigned long long u64;

constexpr int N_ANCH = 100800;
constexpr int DIMV   = 117;    // 4 box + 1 obj + 80 cls + 32 mask
constexpr int NCLS   = 80;
constexpr int TOPKN  = 4096;
constexpr int MAXDET = 300;
constexpr int KCAP   = 12288;
constexpr int NBUCK  = 16384;  // scores < 1.0 -> bits>>16 < 0x3F80 < 16384
constexpr int NBLK   = 256;
constexpr int NTHR   = 256;
constexpr int GSIZE  = NBLK * NTHR;

// packed mask geometry: row-block t (rows [64t,64t+64)) stores words t..63:
// word w of row r=64t+u at maskp[64*(64t - t(t-1)/2) + u*(64-t) + (w-t)].
constexpr int NTILE2 = 2080;   // upper-tri 64x64 tiles = 64*65/2

// workspace layout (bytes)
constexpr size_t WS_HIST   = 0;                                  // 16384 u32
constexpr size_t WS_BAR    = WS_HIST   + 65536;                  // 32 u32
constexpr size_t WS_SEL    = WS_BAR    + 128;                    // 64 i32
constexpr size_t WS_SARR   = WS_SEL    + 256;                    // 300 i32
constexpr size_t WS_SCORES = WS_SARR   + 1472;                   // 100800 f32
constexpr size_t WS_CLS    = WS_SCORES + (size_t)N_ANCH * 4;     // 100800 i32
constexpr size_t WS_KEYS   = WS_CLS    + (size_t)N_ANCH * 4;     // 12288 u64
constexpr size_t WS_RANK   = WS_KEYS   + (size_t)KCAP * 8;       // 12288 i32
constexpr size_t WS_SIDX   = WS_RANK   + (size_t)KCAP * 4;       // 4096 i32
constexpr size_t WS_SSC    = WS_SIDX   + 4096ull * 4;            // 4096 f32
constexpr size_t WS_BOXES  = WS_SSC    + 4096ull * 4;            // 4096*4 f32
constexpr size_t WS_MASKP  = WS_BOXES  + 4096ull * 16;           // packed mask

__global__ void init_kernel(unsigned* __restrict__ hist, int* __restrict__ sel,
                            unsigned* __restrict__ bar) {
    int i = blockIdx.x * 256 + threadIdx.x;
    if (i < NBUCK) hist[i] = 0u;
    if (i < 64)    sel[i]  = 0;
    if (i < 32)    bar[i]  = 0u;
}

__device__ __forceinline__ void gridbar(unsigned* bar, int phase) {
    __syncthreads();
    if (threadIdx.x == 0) {
        __threadfence();   // release: my phase's writes -> coherence point
        __hip_atomic_fetch_add(&bar[phase], 1u, __ATOMIC_ACQ_REL,
                               __HIP_MEMORY_SCOPE_AGENT);
        while (__hip_atomic_load(&bar[phase], __ATOMIC_ACQUIRE,
                                 __HIP_MEMORY_SCOPE_AGENT) < (unsigned)NBLK) {
            __builtin_amdgcn_s_sleep(2);
        }
        __threadfence();   // acquire: don't serve later reads from stale cache
    }
    __syncthreads();
}

__device__ __forceinline__ u64 readlane64(u64 v, int l) {
    unsigned lo = (unsigned)__builtin_amdgcn_readlane((int)(unsigned)(v & 0xFFFFFFFFull), l);
    unsigned hi = (unsigned)__builtin_amdgcn_readlane((int)(unsigned)(v >> 32), l);
    return ((u64)hi << 32) | lo;
}

__global__ void __launch_bounds__(NTHR, 1)
mega_kernel(const float* __restrict__ x, float* __restrict__ out,
            char* __restrict__ ws) {
    unsigned* hist   = (unsigned*)(ws + WS_HIST);
    unsigned* bar    = (unsigned*)(ws + WS_BAR);
    int*      sel    = (int*)(ws + WS_SEL);
    int*      sArrG  = (int*)(ws + WS_SARR);
    float*    scores = (float*)(ws + WS_SCORES);
    int*      cls    = (int*)(ws + WS_CLS);
    u64*      keys   = (u64*)(ws + WS_KEYS);
    int*      rank   = (int*)(ws + WS_RANK);
    int*      sidx   = (int*)(ws + WS_SIDX);
    float*    sscore = (float*)(ws + WS_SSC);
    float*    boxes  = (float*)(ws + WS_BOXES);
    u64*      maskp  = (u64*)(ws + WS_MASKP);

    // 125440 B static LDS: forces 1 block/CU -> 256 blocks co-resident.
    __shared__ __align__(16) char smem[125440];

    // ---- phase 0: scores + LDS-local histogram ---------------------------
    {
        float*    sx = (float*)smem;                  // 128*117 f32 = 59904 B
        unsigned* lh = (unsigned*)(smem + 59904);     // 16384 u32  = 65536 B
        for (int i = threadIdx.x; i < NBUCK; i += NTHR) lh[i] = 0u;
        __syncthreads();
        constexpr int TROWS = 128;
        constexpr int NTILE = (N_ANCH + TROWS - 1) / TROWS;   // 788
        for (int tile = blockIdx.x; tile < NTILE; tile += NBLK) {
            int r0 = tile * TROWS;
            int rows = N_ANCH - r0; if (rows > TROWS) rows = TROWS;
            const float4* src = (const float4*)(x + (size_t)r0 * DIMV); // 128*117%4==0
            float4* dst = (float4*)sx;
            int nv4 = rows * DIMV / 4;
            for (int i = threadIdx.x; i < nv4; i += NTHR) dst[i] = src[i];
            __syncthreads();
            int row = threadIdx.x >> 1, half = threadIdx.x & 1;
            if (row < rows) {
                const float* rp = sx + row * DIMV;
                float obj = rp[4];
                const float* cp = rp + 5 + half * 40;
                float best = -1.0f; int bc = half * 40;
#pragma unroll 8
                for (int c = 0; c < 40; ++c) {
                    float s = __fmul_rn(cp[c], obj);
                    if (s > best) { best = s; bc = half * 40 + c; }
                }
                float so = __shfl_xor(best, 1);
                int   co = __shfl_xor(bc, 1);
                if (half == 0) {
                    if (so > best) { best = so; bc = co; }  // strict >: lower class wins ties
                    int a = r0 + row;
                    bool valid = obj > 0.25f;
                    scores[a] = valid ? best : -1.0f;
                    cls[a] = bc;
                    if (valid) atomicAdd(&lh[__float_as_uint(best) >> 16], 1u);
                }
            }
            __syncthreads();
        }
        for (int b = threadIdx.x; b < NBUCK; b += NTHR) {
            unsigned v = lh[b];
            if (v) atomicAdd(&hist[b], v);        // device atomics: coherent point
        }
    }
    gridbar(bar, 0);

    // ---- phase 1: select bucket B (block 0) ------------------------------
    if (blockIdx.x == 0) {
        unsigned* sv = (unsigned*)smem;               // 256 u32
        int* bsh = (int*)(smem + 2048);               // [0]=t*, [1]=before
        int t = threadIdx.x;
        int base = NBUCK - 64 * (t + 1);              // chunk t = top-descending
        const uint4* hp = (const uint4*)(hist + base);
        unsigned own = 0;
#pragma unroll
        for (int q = 0; q < 16; ++q) { uint4 v = hp[q]; own += v.x + v.y + v.z + v.w; }
        sv[t] = own;
        __syncthreads();
        for (int off = 1; off < 256; off <<= 1) {     // inclusive scan
            unsigned v = (t >= off) ? sv[t - off] : 0u;
            __syncthreads();
            sv[t] += v;
            __syncthreads();
        }
        unsigned incl = sv[t], before = incl - own;
        if (before < (unsigned)TOPKN && incl >= (unsigned)TOPKN) {
            bsh[0] = t; bsh[1] = (int)before;
        }
        __syncthreads();
        if (t == 0) {
            int ts = bsh[0];
            unsigned running = (unsigned)bsh[1];
            int cbase = NBUCK - 64 * (ts + 1);
            unsigned hh[64];
#pragma unroll
            for (int u = 0; u < 64; ++u) hh[u] = hist[cbase + 63 - u]; // independent loads
            for (int u = 0; u < 64; ++u) {
                if (running + hh[u] >= (unsigned)TOPKN) { sel[0] = cbase + 63 - u; break; }
                running += hh[u];
            }
        }
    }
    gridbar(bar, 1);

    // ---- phase 2: compact (bucket >= B) ----------------------------------
    {
        int B = sel[0];
        for (int a = blockIdx.x * NTHR + threadIdx.x; a < N_ANCH; a += GSIZE) {
            float s = scores[a];
            if (s < 0.0f) continue;
            unsigned bits = __float_as_uint(s);
            if ((int)(bits >> 16) < B) continue;
            int pos = atomicAdd(&sel[2], 1);
            // key = (score_bits<<32)|~a: desc key == (score desc, idx asc) == stable top_k
            if (pos < KCAP) keys[pos] = ((u64)bits << 32) | (unsigned)(~a);
        }
    }
    gridbar(bar, 2);

    // ---- phase 3: rank = #{j: key_j > key_i}, single pass, plain write ---
    {
        u64* tile = (u64*)smem;                       // 2048 u64 = 16 KB
        int n = sel[2]; if (n > KCAP) n = KCAP;
        int RB = (n + NTHR - 1) / NTHR;
        for (int rb = blockIdx.x; rb < RB; rb += NBLK) {
            int i = rb * NTHR + threadIdx.x;
            u64 myKey = (i < n) ? keys[i] : 0ull;
            int cnt = 0;
            for (int t0 = 0; t0 < n; t0 += 2048) {
                int m = n - t0; if (m > 2048) m = 2048;
                __syncthreads();
                for (int j = threadIdx.x; j < m; j += NTHR) tile[j] = keys[t0 + j];
                __syncthreads();
                int j = 0;
                for (; j + 3 < m; j += 4) {
                    cnt += (tile[j]     > myKey);
                    cnt += (tile[j + 1] > myKey);
                    cnt += (tile[j + 2] > myKey);
                    cnt += (tile[j + 3] > myKey);
                }
                for (; j < m; ++j) cnt += (tile[j] > myKey);
            }
            if (i < n) rank[i] = cnt;                 // ranks 0..4095 = sorted top-4096
        }
    }
    gridbar(bar, 3);

    // ---- phase 4: scatter by rank + box decode (no fma) ------------------
    {
        int n = sel[2]; if (n > KCAP) n = KCAP;
        for (int i = blockIdx.x * NTHR + threadIdx.x; i < n; i += GSIZE) {
            int r = rank[i];
            if (r >= TOPKN) continue;
            u64 k = keys[i];
            int a = (int)(~(unsigned)(k & 0xFFFFFFFFull));
            sidx[r] = a;
            sscore[r] = __uint_as_float((unsigned)(k >> 32));
            const float* p = x + (size_t)a * DIMV;
            float xc = p[0], yc = p[1], w = p[2], h = p[3];
            float hw = __fmul_rn(w, 0.5f);
            float hh = __fmul_rn(h, 0.5f);
            boxes[r * 4 + 0] = __fsub_rn(yc, hh);
            boxes[r * 4 + 1] = __fsub_rn(xc, hw);
            boxes[r * 4 + 2] = __fadd_rn(yc, hh);
            boxes[r * 4 + 3] = __fadd_rn(xc, hw);
        }
    }
    gridbar(bar, 4);

    // ---- phase 5: packed upper-tri IoU bitmask ---------------------------
    {
        float (*cb)[64][5] = (float (*)[64][5])smem;  // 4 sub-waves x 1280 B
        int sw = threadIdx.x >> 6, t = threadIdx.x & 63;
        // 2080 = 520*4 tiles; per block-iteration all 4 sub-waves valid.
        for (int k0 = blockIdx.x * 4; k0 < NTILE2; k0 += NBLK * 4) {
            int k = k0 + sw;
            // k -> (rowT, colT): S(t)=t*(129-t)/2; rowT: S(rowT)<=k<S(rowT+1)
            double disc = 129.0 * 129.0 - 8.0 * (double)k;
            int rowT = (int)((129.0 - sqrt(disc)) * 0.5);
            while ((rowT + 1) * (129 - (rowT + 1)) / 2 <= k) ++rowT;
            while (rowT * (129 - rowT) / 2 > k) --rowT;
            int colT = rowT + (k - rowT * (129 - rowT) / 2);
            const float4* bp = (const float4*)boxes;
            {
                float4 c = bp[colT * 64 + t];
                cb[sw][t][0] = c.x; cb[sw][t][1] = c.y;
                cb[sw][t][2] = c.z; cb[sw][t][3] = c.w;
                cb[sw][t][4] = __fmul_rn(__fsub_rn(c.z, c.x), __fsub_rn(c.w, c.y));
            }
            __syncthreads();
            int r = rowT * 64 + t;
            float4 rv = bp[r];
            float ry1 = rv.x, rx1 = rv.y, ry2 = rv.z, rx2 = rv.w;
            float rarea = __fmul_rn(__fsub_rn(ry2, ry1), __fsub_rn(rx2, rx1));
            u64 bitsw = 0ull;
#pragma unroll 8
            for (int j = 0; j < 64; ++j) {
                float iy1 = fmaxf(ry1, cb[sw][j][0]);
                float ix1 = fmaxf(rx1, cb[sw][j][1]);
                float iy2 = fminf(ry2, cb[sw][j][2]);
                float ix2 = fminf(rx2, cb[sw][j][3]);
                float ih = fmaxf(__fsub_rn(iy2, iy1), 0.0f);
                float iw = fmaxf(__fsub_rn(ix2, ix1), 0.0f);
                float inter = __fmul_rn(ih, iw);
                float uni = __fsub_rn(__fadd_rn(rarea, cb[sw][j][4]), inter);
                float iou = __fdiv_rn(inter, fmaxf(uni, 1e-9f));
                if (iou > 0.45f && (colT * 64 + j) > r) bitsw |= (1ull << j);
            }
            int pb = 64 * (64 * rowT - (rowT * (rowT - 1)) / 2);
            maskp[pb + t * (64 - rowT) + (colT - rowT)] = bitsw;
            __syncthreads();
        }
    }
    gridbar(bar, 5);

    // ---- phase 6: speculative greedy scan (block 0, one wave) ------------
    if (blockIdx.x == 0 && threadIdx.x < 64) {
        int lane = threadIdx.x;
        u64 alive = ~0ull;                // lane owns candidates [64*lane, 64*lane+64)
        int count = 0, scanPtr = 0, emptyRun = 0;
        int q[16]; u64 d[16];

        auto findNext = [&](int sp) -> int {
            if (sp >= TOPKN) return TOPKN;
            u64 m = alive;
            int wsrd = sp >> 6;
            if (lane == wsrd) m &= (~0ull) << (sp & 63);
            if (lane < wsrd)  m = 0ull;
            u64 bal = __ballot(m != 0ull);
            if (!bal) return TOPKN;
            int l0 = (int)__builtin_ctzll(bal);
            u64 w = readlane64(m, l0);
            return l0 * 64 + (int)__builtin_ctzll(w);
        };
        auto loadRow = [&](int c) -> u64 {  // speculative per-lane row load
            int rT = c >> 6;
            int strd = 64 - rT;
            int rel = lane - rT; if (rel < 0) rel = 0;      // masked at use
            size_t idx = (size_t)(64 * (64 * rT - (rT * (rT - 1)) / 2))
                       + (size_t)(c & 63) * strd + rel;
            return maskp[idx];              // backend emits counted vmcnt at use
        };

#pragma unroll
        for (int s = 0; s < 16; ++s) {      // prefill FIFO
            int c = findNext(scanPtr);
            q[s] = c;
            if (c < TOPKN) { scanPtr = c + 1; d[s] = loadRow(c); }
            else d[s] = 0ull;
        }
        bool done = false;
        while (!done) {
#pragma unroll
            for (int s = 0; s < 16; ++s) {
                int c = q[s];
                if (c >= TOPKN) {           // empty slot; 16 consecutive -> drained
                    if (++emptyRun >= 16) { done = true; break; }
                    continue;
                }
                emptyRun = 0;
                u64 aw = readlane64(alive, c >> 6);
                if ((aw >> (c & 63)) & 1ull) {          // still alive -> KEEP
                    u64 row = (lane >= (c >> 6)) ? d[s] : 0ull;
                    alive &= ~row;                      // suppress (bits > c only)
                    if (lane == 0) sArrG[count] = c;
                    ++count;
                    if (count >= MAXDET) { done = true; break; }
                }
                int nc = findNext(scanPtr);             // refill slot s
                q[s] = nc;
                if (nc < TOPKN) { scanPtr = nc + 1; d[s] = loadRow(nc); }
            }
        }
        if (lane == 0) {
            sel[3] = count;
            if (count < MAXDET) {           // fillers: suppressed (= ~alive) ascending
                int filled = count;
                for (int w2 = 0; w2 < 64 && filled < MAXDET; ++w2) {
                    u64 word = ~readlane64(alive, w2);
                    while (word && filled < MAXDET) {
                        int b = (int)__builtin_ctzll(word);
                        word &= word - 1;
                        sArrG[filled++] = (w2 << 6) + b;
                    }
                }
            }
        }
    }
    gridbar(bar, 6);

    // ---- phase 7: output boxes[300*4] | classes | scores | masks[300*32] -
    {
        int K = sel[3];
        int gtid = blockIdx.x * NTHR + threadIdx.x;
        int o = gtid >> 5, t32 = gtid & 31;
        if (o < MAXDET) {
            int s = sArrG[o];
            int a = sidx[s];
            out[1800 + o * 32 + t32] = x[(size_t)a * DIMV + 85 + t32];
            if (t32 < 4)       out[o * 4 + t32] = boxes[s * 4 + t32];
            else if (t32 == 4) out[1200 + o] = (float)cls[a];
            else if (t32 == 5) out[1500 + o] = (o < K) ? sscore[s] : -1.0f;
        }
    }
}

extern "C" void kernel_launch(void* const* d_in, const int* in_sizes, int n_in,
                              void* d_out, int out_size, void* d_ws, size_t ws_size,
                              hipStream_t stream) {
    const float* x = (const float*)d_in[0];
    char* ws = (char*)d_ws;
    unsigned* hist = (unsigned*)(ws + WS_HIST);
    unsigned* bar  = (unsigned*)(ws + WS_BAR);
    int*      sel  = (int*)(ws + WS_SEL);

    init_kernel<<<64, 256, 0, stream>>>(hist, sel, bar);
    mega_kernel<<<NBLK, NTHR, 0, stream>>>(x, (float*)d_out, ws);
}

// Round 6
// 441.207 us; speedup vs baseline: 1.8472x; 1.8472x over previous
//
#include <hip/hip_runtime.h>

// ---------------------------------------------------------------------------
// YOLO NMS post-processing for MI355X — 7-launch pipeline.
//   zero -> score (+16-way sliced hist) -> reduce+select (last-block
//   handshake) -> compact -> rank+scatter (single-pass, no rank buffer) ->
//   packed IoU mask -> speculative-FIFO greedy scan + fused output.
//
// Round-5 lessons: mega-kernel grid barriers serialize the GPU (815 us) but
// proved device-scope fence+atomic handshakes are safe cross-XCD; round 1-4:
// the 64-batch serial scan loop is invariantly 41-48 us across structures ->
// this round replaces batch-granularity with candidate-granularity:
//   alive = 4096 bits (1 u64/lane, lane L owns slots [64L, 64L+64)).
//   8-deep register FIFO of speculatively loaded candidate mask rows (plain
//   per-lane coalesced loads; compiler emits counted vmcnt). Pop head ->
//   readlane alive-test -> if alive: KEEP, suppress via alive &= ~row (row
//   already in registers); dead pops cost ~nothing. Refill = wave-ballot
//   find-next-alive-bit. Pops ~= keeps + in-window discards. Greedy order ==
//   reference: pops ascend in slot order and every prior keep's suppression
//   is applied before a later candidate is tested. Kept bits stay set in
//   alive (mask rows only carry j>r), so suppressed == ~alive exactly ->
//   fillers (score -1, ascending slots) read straight from ~alive.
//
// All IoU-relevant fp32 math uses _rn intrinsics so hipcc's default
// -ffp-contract=fast cannot fuse mul+add into fma (must match numpy fp32).
// ---------------------------------------------------------------------------

#define AS1 __attribute__((address_space(1)))
#define AS3 __attribute__((address_space(3)))

typedef unsigned long long u64;

constexpr int N_ANCH = 100800;
constexpr int DIMV   = 117;   // 4 box + 1 obj + 80 cls + 32 mask
constexpr int TOPKN  = 4096;
constexpr int MAXDET = 300;
constexpr int KCAP   = 12288; // candidate capacity
constexpr int NBUCK  = 16384; // scores < 1.0 -> bits>>16 < 0x3F80 < 16384
constexpr int NSLICE = 16;
constexpr int FDEPTH = 8;     // scan FIFO depth (bounds worst-case discards)

// packed mask geometry: row-block t (rows [64t,64t+64)) stores words t..63
// contiguously: 64 rows x (64-t) u64. pbase64(t) = 64 * (64t - t(t-1)/2).
constexpr int PACK_TOT = 133120;                  // 64 * 2080 u64

// workspace layout (bytes)
constexpr size_t WS_HIST   = 0;                                   // 16384 u32
constexpr size_t WS_SEL    = WS_HIST   + 65536;                   // 64 i32
constexpr size_t WS_DONE   = WS_SEL    + 256;                     // 1 u32 (+pad)
constexpr size_t WS_SLICES = WS_DONE   + 256;                     // 16*16384 u32
constexpr size_t WS_SCORES = WS_SLICES + (size_t)NSLICE * NBUCK * 4;
constexpr size_t WS_CLS    = WS_SCORES + (size_t)N_ANCH * 4;
constexpr size_t WS_KEYS   = WS_CLS    + (size_t)N_ANCH * 4;      // 12288 u64
constexpr size_t WS_SIDX   = WS_KEYS   + (size_t)KCAP * 8;        // 4096 i32
constexpr size_t WS_SSC    = WS_SIDX   + 4096ull * 4;             // 4096 f32
constexpr size_t WS_BOXES  = WS_SSC    + 4096ull * 4;             // 4096*4 f32
constexpr size_t WS_MASKP  = WS_BOXES  + 4096ull * 16;            // packed mask

__global__ void zero_kernel(unsigned* __restrict__ slices, int* __restrict__ sel,
                            unsigned* __restrict__ done) {
    int i = blockIdx.x * 256 + threadIdx.x;
    if (i < NSLICE * NBUCK) slices[i] = 0u;
    if (i < 64)             sel[i]    = 0;
    if (i == 0)             *done     = 0u;
}

// 64 rows per 128-thread block, staged to LDS with coalesced float4 loads.
// 2 threads per row: even lane scans classes 0..39, odd lane 40..79, merged
// via shfl_xor. Strict > keeps the first (lowest-class) argmax like numpy.
constexpr int SROWS = 64;
__global__ void score_kernel(const float* __restrict__ x, float* __restrict__ scores,
                             int* __restrict__ cls, unsigned* __restrict__ slices) {
    __shared__ float sx[SROWS * DIMV];           // 29952 B
    int block0 = blockIdx.x * SROWS;
    const float4* src = (const float4*)(x + (size_t)block0 * DIMV); // 64*468 % 16 == 0
    float4* dst = (float4*)sx;
    constexpr int NV4 = SROWS * DIMV / 4;        // 1872
    for (int i = threadIdx.x; i < NV4; i += 128) dst[i] = src[i];
    __syncthreads();
    int row  = threadIdx.x >> 1;
    int half = threadIdx.x & 1;
    const float* rp = sx + row * DIMV;
    float obj = rp[4];
    const float* cp = rp + 5 + half * 40;
    float best = -1.0f;
    int   bc   = half * 40;
#pragma unroll 8
    for (int c = 0; c < 40; ++c) {
        float s = __fmul_rn(cp[c], obj);
        if (s > best) { best = s; bc = half * 40 + c; }
    }
    float so = __shfl_xor(best, 1);
    int   co = __shfl_xor(bc, 1);
    if (half == 0) {
        if (so > best) { best = so; bc = co; }   // strict >: even (lower classes) wins ties
        int a = block0 + row;
        bool valid = obj > 0.25f;
        scores[a] = valid ? best : -1.0f;
        cls[a]    = bc;
        if (valid) {
            unsigned b = __float_as_uint(best) >> 16;   // < 16384 (best in [0,1))
            atomicAdd(&slices[(blockIdx.x & (NSLICE - 1)) * NBUCK + b], 1u);
        }
    }
}

// fold 16 slices -> hist (64 blocks x 256), then the LAST block (device-scope
// ticket; round-5 evidence: threadfence release/acquire + agent atomics are
// cross-XCD safe) runs select: find bucket B with
// cntAbove(B) < 4096 <= cntAbove(B)+hist[B]. Thread t owns 64 buckets.
__global__ void reduce_select_kernel(const unsigned* __restrict__ slices,
                                     unsigned* __restrict__ hist,
                                     int* __restrict__ sel,
                                     unsigned* __restrict__ done) {
    int b = blockIdx.x * 256 + threadIdx.x;
    unsigned s = 0;
#pragma unroll
    for (int k = 0; k < NSLICE; ++k) s += slices[(size_t)k * NBUCK + b];
    hist[b] = s;
    __threadfence();                      // release hist writes
    __syncthreads();
    __shared__ unsigned tick;
    if (threadIdx.x == 0)
        tick = __hip_atomic_fetch_add(done, 1u, __ATOMIC_ACQ_REL,
                                      __HIP_MEMORY_SCOPE_AGENT);
    __syncthreads();
    if (tick != 63) return;               // not the last block
    __threadfence();                      // acquire: fresh hist reads

    __shared__ unsigned sv[256];
    __shared__ int bsh[2];
    int t = threadIdx.x;
    int base = NBUCK - 64 * (t + 1);      // chunk t = 64 buckets, t=0 = top
    const uint4* hp = (const uint4*)(hist + base);
    unsigned own = 0;
#pragma unroll
    for (int q = 0; q < 16; ++q) { uint4 v = hp[q]; own += v.x + v.y + v.z + v.w; }
    sv[t] = own;
    __syncthreads();
    for (int off = 1; off < 256; off <<= 1) {     // inclusive scan (desc-chunk order)
        unsigned v = (t >= off) ? sv[t - off] : 0u;
        __syncthreads();
        sv[t] += v;
        __syncthreads();
    }
    unsigned incl = sv[t], before = incl - own;
    if (before < (unsigned)TOPKN && incl >= (unsigned)TOPKN) {
        bsh[0] = t; bsh[1] = (int)before;
    }
    __syncthreads();
    if (t == 0) {
        int ts = bsh[0];
        unsigned running = (unsigned)bsh[1];
        int cbase = NBUCK - 64 * (ts + 1);
        unsigned hh[64];
#pragma unroll
        for (int u = 0; u < 64; ++u) hh[u] = hist[cbase + 63 - u];  // independent loads
        for (int u = 0; u < 64; ++u) {
            if (running + hh[u] >= (unsigned)TOPKN) { sel[0] = cbase + 63 - u; break; }
            running += hh[u];
        }
    }
}

// compact all anchors with bucket >= B into keys[]; key = (score_bits<<32)|~a
// -> descending key order == (score desc, idx asc) == stable top_k order.
__global__ void compact_kernel(const float* __restrict__ scores, int* sel,
                               u64* __restrict__ keys) {
    int a = blockIdx.x * blockDim.x + threadIdx.x;
    if (a >= N_ANCH) return;
    float s = scores[a];
    if (s < 0.0f) return;
    unsigned bits = __float_as_uint(s);
    if ((int)(bits >> 16) < sel[0]) return;
    int pos = atomicAdd(&sel[2], 1);
    if (pos < KCAP) keys[pos] = ((u64)bits << 32) | (unsigned)(~a);
}

// fused rank + scatter, single pass: rank[i] = #{j: key_j > key_i} computed
// fully per thread (keys unique -> ranks a permutation; 0..4095 = top-4096),
// then scatter + box decode inline. No rank buffer, no zeroing, no atomics.
__global__ void rank_scatter_kernel(const float* __restrict__ x,
                                    const u64* __restrict__ keys,
                                    const int* __restrict__ sel,
                                    int* __restrict__ sidx, float* __restrict__ sscore,
                                    float* __restrict__ boxes) {
    __shared__ u64 tile[2048];
    int n = sel[2]; if (n > KCAP) n = KCAP;
    if (blockIdx.x * 256 >= n) return;
    int i = blockIdx.x * 256 + threadIdx.x;
    u64 myKey = (i < n) ? keys[i] : 0ull;
    int cnt = 0;
    for (int t0 = 0; t0 < n; t0 += 2048) {
        int m = n - t0; if (m > 2048) m = 2048;
        __syncthreads();
        for (int j = threadIdx.x; j < m; j += 256) tile[j] = keys[t0 + j];
        __syncthreads();
        int j = 0;
        for (; j + 3 < m; j += 4) {
            cnt += (tile[j]     > myKey);
            cnt += (tile[j + 1] > myKey);
            cnt += (tile[j + 2] > myKey);
            cnt += (tile[j + 3] > myKey);
        }
        for (; j < m; ++j) cnt += (tile[j] > myKey);
    }
    if (i >= n || cnt >= TOPKN) return;
    int r = cnt;
    u64 k = myKey;
    int a = (int)(~(unsigned)(k & 0xFFFFFFFFull));
    sidx[r]   = a;
    sscore[r] = __uint_as_float((unsigned)(k >> 32));
    const float* p = x + (size_t)a * DIMV;
    float xc = p[0], yc = p[1], w = p[2], h = p[3];
    float hw = __fmul_rn(w, 0.5f);
    float hh = __fmul_rn(h, 0.5f);
    boxes[r * 4 + 0] = __fsub_rn(yc, hh);
    boxes[r * 4 + 1] = __fsub_rn(xc, hw);
    boxes[r * 4 + 2] = __fadd_rn(yc, hh);
    boxes[r * 4 + 3] = __fadd_rn(xc, hw);
}

// 64x64 tile IoU bitmask, PACKED upper triangle only. Row-block rowT stores
// words rowT..63: row r=64*rowT+t word colT lives at
//   maskp[pbase64(rowT) + t*(64-rowT) + (colT-rowT)].
// Lower-triangle blocks write NOTHING (mask bits are j>r only).
__global__ void iou_mask_kernel(const float* __restrict__ boxes,
                                u64* __restrict__ maskp) {
    int colT = blockIdx.x, rowT = blockIdx.y;
    if (colT < rowT) return;                 // never materialized
    int t = threadIdx.x;                     // 0..63
    __shared__ float cb[64][5];
    const float4* bp = (const float4*)boxes; // y1 x1 y2 x2, 16B-aligned
    int cj = colT * 64 + t;
    {
        float4 c = bp[cj];
        cb[t][0] = c.x; cb[t][1] = c.y; cb[t][2] = c.z; cb[t][3] = c.w;
        cb[t][4] = __fmul_rn(__fsub_rn(c.z, c.x), __fsub_rn(c.w, c.y));
    }
    __syncthreads();
    int r = rowT * 64 + t;
    float4 rv = bp[r];
    float ry1 = rv.x, rx1 = rv.y, ry2 = rv.z, rx2 = rv.w;
    float rarea = __fmul_rn(__fsub_rn(ry2, ry1), __fsub_rn(rx2, rx1));
    u64 bitsw = 0ull;
#pragma unroll 8
    for (int j = 0; j < 64; ++j) {
        float iy1 = fmaxf(ry1, cb[j][0]);
        float ix1 = fmaxf(rx1, cb[j][1]);
        float iy2 = fminf(ry2, cb[j][2]);
        float ix2 = fminf(rx2, cb[j][3]);
        float ih = fmaxf(__fsub_rn(iy2, iy1), 0.0f);
        float iw = fmaxf(__fsub_rn(ix2, ix1), 0.0f);
        float inter = __fmul_rn(ih, iw);
        float uni = __fsub_rn(__fadd_rn(rarea, cb[j][4]), inter);
        float iou = __fdiv_rn(inter, fmaxf(uni, 1e-9f));
        if (iou > 0.45f && (colT * 64 + j) > r) bitsw |= (1ull << j);
    }
    int pb = 64 * (64 * rowT - (rowT * (rowT - 1)) / 2);
    maskp[pb + t * (64 - rowT) + (colT - rowT)] = bitsw;
}

__device__ __forceinline__ u64 readlane64(u64 v, int l) {
    unsigned lo = (unsigned)__builtin_amdgcn_readlane((int)(unsigned)(v & 0xFFFFFFFFull), l);
    unsigned hi = (unsigned)__builtin_amdgcn_readlane((int)(unsigned)(v >> 32), l);
    return ((u64)hi << 32) | lo;
}

// Speculative-FIFO greedy scan (wave 0) + fused output (all 4 waves).
__global__ void __launch_bounds__(256, 1)
nms_scan_kernel(const u64* __restrict__ maskp,
                const float* __restrict__ sscore,
                const float* __restrict__ x,
                const int* __restrict__ sidx,
                const int* __restrict__ cls,
                const float* __restrict__ boxes,
                float* __restrict__ out) {
    __shared__ int sArrL[MAXDET];
    __shared__ int KK;

    if (threadIdx.x < 64) {                  // ---- wave 0: the scan ----
        int lane = threadIdx.x;
        u64 alive = ~0ull;                   // lane L owns slots [64L, 64L+64)
        int count = 0, scanPtr = 0, emptyRun = 0;
        int q[FDEPTH]; u64 d[FDEPTH];

        auto findNext = [&](int sp) -> int { // next alive slot >= sp (uniform)
            if (sp >= TOPKN) return TOPKN;
            u64 m = alive;
            int wsrd = sp >> 6;
            if (lane == wsrd) m &= (~0ull) << (sp & 63);
            if (lane < wsrd)  m = 0ull;
            u64 bal = __ballot(m != 0ull);
            if (!bal) return TOPKN;
            int l0 = (int)__builtin_ctzll(bal);
            u64 w = readlane64(m, l0);
            return l0 * 64 + (int)__builtin_ctzll(w);
        };
        auto loadRow = [&](int c) -> u64 {   // speculative per-lane row load
            int rT = c >> 6;
            int strd = 64 - rT;
            int rel = lane - rT; if (rel < 0) rel = 0;    // masked at use
            size_t idx = (size_t)(64 * (64 * rT - (rT * (rT - 1)) / 2))
                       + (size_t)(c & 63) * strd + rel;
            return maskp[idx];               // compiler emits counted vmcnt at use
        };

#pragma unroll
        for (int s = 0; s < FDEPTH; ++s) {   // prefill FIFO (ascending slots)
            int c = findNext(scanPtr);
            q[s] = c;
            if (c < TOPKN) { scanPtr = c + 1; d[s] = loadRow(c); }
            else d[s] = 0ull;
        }
        bool done = false;
        while (!done) {
#pragma unroll
            for (int s = 0; s < FDEPTH; ++s) {
                int c = q[s];
                if (c >= TOPKN) {            // empty slot; FDEPTH in a row -> drained
                    if (++emptyRun >= FDEPTH) { done = true; break; }
                    continue;
                }
                emptyRun = 0;
                u64 aw = readlane64(alive, c >> 6);
                if ((aw >> (c & 63)) & 1ull) {            // still alive -> KEEP
                    u64 row = (lane >= (c >> 6)) ? d[s] : 0ull;
                    alive &= ~row;                        // bits > c only; c stays set
                    if (lane == 0) sArrL[count] = c;
                    ++count;
                    if (count >= MAXDET) { done = true; break; }
                }
                int nc = findNext(scanPtr);               // refill slot s
                q[s] = nc;
                if (nc < TOPKN) { scanPtr = nc + 1; d[s] = loadRow(nc); }
            }
        }
        if (lane == 0) {
            KK = count;
            if (count < MAXDET) {            // fillers: suppressed == ~alive, ascending
                int filled = count;
                for (int w2 = 0; w2 < 64 && filled < MAXDET; ++w2) {
                    u64 word = ~readlane64(alive, w2);
                    while (word && filled < MAXDET) {
                        int b = (int)__builtin_ctzll(word);
                        word &= word - 1;
                        sArrL[filled++] = (w2 << 6) + b;
                    }
                }
            }
        }
    }
    __syncthreads();

    // ---- output: boxes[300*4] | classes[300] | scores[300] | masks[300*32]
    int K = KK;
    int t32 = threadIdx.x & 31;
    for (int o = threadIdx.x >> 5; o < MAXDET; o += 8) {
        int s = sArrL[o];
        int a = sidx[s];
        out[1800 + o * 32 + t32] = x[(size_t)a * DIMV + 85 + t32];
        if (t32 < 4)       out[o * 4 + t32] = boxes[s * 4 + t32];
        else if (t32 == 4) out[1200 + o] = (float)cls[a];
        else if (t32 == 5) out[1500 + o] = (o < K) ? sscore[s] : -1.0f;
    }
}

extern "C" void kernel_launch(void* const* d_in, const int* in_sizes, int n_in,
                              void* d_out, int out_size, void* d_ws, size_t ws_size,
                              hipStream_t stream) {
    const float* x = (const float*)d_in[0];
    char* ws = (char*)d_ws;
    unsigned* hist   = (unsigned*)(ws + WS_HIST);
    int*      sel    = (int*)(ws + WS_SEL);
    unsigned* done   = (unsigned*)(ws + WS_DONE);
    unsigned* slices = (unsigned*)(ws + WS_SLICES);
    float*    scores = (float*)(ws + WS_SCORES);
    int*      cls    = (int*)(ws + WS_CLS);
    u64*      keys   = (u64*)(ws + WS_KEYS);
    int*      sidx   = (int*)(ws + WS_SIDX);
    float*    sscore = (float*)(ws + WS_SSC);
    float*    boxes  = (float*)(ws + WS_BOXES);
    u64*      maskp  = (u64*)(ws + WS_MASKP);

    zero_kernel<<<(NSLICE * NBUCK + 255) / 256, 256, 0, stream>>>(slices, sel, done);
    score_kernel<<<N_ANCH / SROWS, 128, 0, stream>>>(x, scores, cls, slices);
    reduce_select_kernel<<<NBUCK / 256, 256, 0, stream>>>(slices, hist, sel, done);
    compact_kernel<<<(N_ANCH + 255) / 256, 256, 0, stream>>>(scores, sel, keys);
    rank_scatter_kernel<<<KCAP / 256, 256, 0, stream>>>(x, keys, sel, sidx, sscore, boxes);
    dim3 mg(64, 64);
    iou_mask_kernel<<<mg, 64, 0, stream>>>(boxes, maskp);
    nms_scan_kernel<<<1, 256, 0, stream>>>(maskp, sscore, x, sidx, cls, boxes,
                                           (float*)d_out);
}